// Round 1
// baseline (288.625 us; speedup 1.0000x reference)
//
#include <hip/hip_runtime.h>
#include <hip/hip_bf16.h>
#include <math.h>

// B=32, L1=L2=512, H=768.  All-fp16 MFMA pipeline, 6 dispatches:
//   1. cvt_xy:   xh,yh = fp16(x), fp16(y)            (fused, grid.y selects)
//   2. cvt W:    Wh = fp16(W)
//   3. proj:     Px = fp16(relu(xh@Wh^T+b)), Py same  (fused, grid.z selects)
//   4. scores_softmax: alpha = fp16(softmax(mask(Px@Py^T)))  -- S never
//      touches memory: S-tile stays in MFMA accumulators, row max/sum via
//      16-lane shfl_xor + LDS cross-wave reduce (8 waves x 64-col slabs).
//   5. yT:       per-batch transpose of yh (fp16 in, fp16 out)
//   6. attn:     out = alpha @ yT, fp32
//
// fp16 input rounding gives logit noise ~0.006 std (vs 0.099 threshold).
// All GEMM staging is global_load_lds width=16 into unpadded 64B LDS rows.

typedef _Float16 f16x8 __attribute__((ext_vector_type(8)));
typedef float f32x4 __attribute__((ext_vector_type(4)));

__device__ __forceinline__ void gld_lds16(const void* g, void* l) {
  __builtin_amdgcn_global_load_lds(
      (const __attribute__((address_space(1))) unsigned*)g,
      (__attribute__((address_space(3))) unsigned*)l, 16, 0, 0);
}

// ---------------- fp32 -> fp16 convert: x and y in one launch -------------
__global__ __launch_bounds__(256) void cvt_xy_kernel(
    const float* __restrict__ x, const float* __restrict__ y,
    _Float16* __restrict__ xh, _Float16* __restrict__ yh) {
  const float* src = blockIdx.y ? y : x;
  _Float16* dst = blockIdx.y ? yh : xh;
  size_t i = ((size_t)blockIdx.x * 256 + threadIdx.x) * 8;
  float4 a = *(const float4*)&src[i];
  float4 b = *(const float4*)&src[i + 4];
  _Float16 h[8] = {(_Float16)a.x, (_Float16)a.y, (_Float16)a.z, (_Float16)a.w,
                   (_Float16)b.x, (_Float16)b.y, (_Float16)b.z, (_Float16)b.w};
  *(uint4*)&dst[i] = *(uint4*)h;
}

// ---------------- fp32 -> fp16 convert (W) --------------------------------
__global__ __launch_bounds__(256) void cvt_f16_kernel(
    const float* __restrict__ src, _Float16* __restrict__ dst) {
  size_t i = ((size_t)blockIdx.x * 256 + threadIdx.x) * 8;
  float4 a = *(const float4*)&src[i];
  float4 b = *(const float4*)&src[i + 4];
  _Float16 h[8] = {(_Float16)a.x, (_Float16)a.y, (_Float16)a.z, (_Float16)a.w,
                   (_Float16)b.x, (_Float16)b.y, (_Float16)b.z, (_Float16)b.w};
  *(uint4*)&dst[i] = *(uint4*)h;
}

// ---- proj: P[16384,768] = fp16(relu(A @ W^T + b)), K=768, NT fp16 GEMM ----
// blockIdx.z: 0 -> (xh -> Px), 1 -> (yh -> Py)
__global__ __launch_bounds__(256) void proj_mfma_kernel(
    const _Float16* __restrict__ Xh, const _Float16* __restrict__ Yh,
    const _Float16* __restrict__ W, const float* __restrict__ bias,
    _Float16* __restrict__ Px, _Float16* __restrict__ Py) {
  const int K = 768, N = 768;
  const _Float16* A = blockIdx.z ? Yh : Xh;
  _Float16* P = blockIdx.z ? Py : Px;
  __shared__ _Float16 As[128 * 32], Bs[128 * 32];
  int bm = blockIdx.x * 128, bn = blockIdx.y * 128;
  int tid = threadIdx.x, lane = tid & 63, wave = tid >> 6;
  int wm = (wave & 1) * 64, wn = (wave >> 1) * 64;
  int fr = lane & 15, fk = (lane >> 4) * 8;
  int lrow = lane >> 2, lcol = (lane & 3) << 3;

  f32x4 acc[4][4];
#pragma unroll
  for (int i = 0; i < 4; ++i)
#pragma unroll
    for (int j = 0; j < 4; ++j)
#pragma unroll
      for (int e = 0; e < 4; ++e) acc[i][j][e] = 0.f;

  for (int k0 = 0; k0 < K; k0 += 32) {
    __syncthreads();
#pragma unroll
    for (int t = 0; t < 2; ++t) {
      int row = wave * 32 + t * 16;
      gld_lds16(&A[(size_t)(bm + row + lrow) * K + k0 + lcol], &As[row * 32]);
      gld_lds16(&W[(size_t)(bn + row + lrow) * K + k0 + lcol], &Bs[row * 32]);
    }
    __syncthreads();
    f16x8 a[4], bb[4];
#pragma unroll
    for (int i = 0; i < 4; ++i) {
      a[i] = *(const f16x8*)&As[(wm + i * 16 + fr) * 32 + fk];
      bb[i] = *(const f16x8*)&Bs[(wn + i * 16 + fr) * 32 + fk];
    }
#pragma unroll
    for (int i = 0; i < 4; ++i)
#pragma unroll
      for (int j = 0; j < 4; ++j)
        acc[i][j] = __builtin_amdgcn_mfma_f32_16x16x32_f16(a[i], bb[j], acc[i][j], 0, 0, 0);
  }
#pragma unroll
  for (int i = 0; i < 4; ++i)
#pragma unroll
    for (int r = 0; r < 4; ++r) {
      int m = bm + wm + i * 16 + (lane >> 4) * 4 + r;
#pragma unroll
      for (int j = 0; j < 4; ++j) {
        int n = bn + wn + j * 16 + fr;
        P[(size_t)m * N + n] = (_Float16)fmaxf(acc[i][j][r] + bias[n], 0.f);
      }
    }
}

// ---- fused scores+softmax: alpha[b,512,512] = softmax(mask(Px@Py^T)) -----
// Block: 64 rows x 512 cols, 8 waves (wave w -> cols [64w, 64w+64)).
// S-tile never leaves registers; row stats via shfl_xor(1,2,4,8) within the
// 16-lane C-column group + LDS reduce across the 8 waves.
__global__ __launch_bounds__(512) void scores_softmax_kernel(
    const _Float16* __restrict__ Px, const _Float16* __restrict__ Py,
    const int* __restrict__ mask, _Float16* __restrict__ Alpha) {
  const int K = 768, L = 512;
  __shared__ _Float16 As[64 * 32];
  __shared__ _Float16 Bs[512 * 32];
  __shared__ float redm[8][64], reds[8][64];
  int b = blockIdx.y;
  size_t pb = (size_t)b * L * K;
  const int* mk = mask + (size_t)b * L;
  _Float16* Ab = Alpha + (size_t)b * L * L;
  int bm = blockIdx.x * 64;
  int tid = threadIdx.x, lane = tid & 63, wave = tid >> 6;
  int wn = wave * 64;
  int fr = lane & 15, fk = (lane >> 4) * 8;
  int lrow = lane >> 2, lcol = (lane & 3) << 3;

  f32x4 acc[4][4];
#pragma unroll
  for (int i = 0; i < 4; ++i)
#pragma unroll
    for (int j = 0; j < 4; ++j)
#pragma unroll
      for (int e = 0; e < 4; ++e) acc[i][j][e] = 0.f;

  for (int k0 = 0; k0 < K; k0 += 32) {
    __syncthreads();
#pragma unroll
    for (int t = 0; t < 4; ++t) {
      int row = wave * 64 + t * 16;  // Bs holds all 512 Py rows (= S cols)
      gld_lds16(&Py[pb + (size_t)(row + lrow) * K + k0 + lcol], &Bs[row * 32]);
    }
    if (wave < 4) {
      int row = wave * 16;
      gld_lds16(&Px[pb + (size_t)(bm + row + lrow) * K + k0 + lcol], &As[row * 32]);
    }
    __syncthreads();
    f16x8 a[4], bb[4];
#pragma unroll
    for (int i = 0; i < 4; ++i) {
      a[i] = *(const f16x8*)&As[(i * 16 + fr) * 32 + fk];
      bb[i] = *(const f16x8*)&Bs[(wn + i * 16 + fr) * 32 + fk];
    }
#pragma unroll
    for (int i = 0; i < 4; ++i)
#pragma unroll
      for (int j = 0; j < 4; ++j)
        acc[i][j] = __builtin_amdgcn_mfma_f32_16x16x32_f16(a[i], bb[j], acc[i][j], 0, 0, 0);
  }

  // ---- softmax epilogue, all in registers ----
  int mki[4];
#pragma unroll
  for (int j = 0; j < 4; ++j) mki[j] = mk[wn + j * 16 + fr];
#pragma unroll
  for (int i = 0; i < 4; ++i)
#pragma unroll
    for (int j = 0; j < 4; ++j)
      if (mki[j]) {
#pragma unroll
        for (int r = 0; r < 4; ++r) acc[i][j][r] = -INFINITY;
      }

  int g4 = (lane >> 4) << 2;
  // per-row max: 4 in-lane + 16-lane butterfly, then cross-wave via LDS
#pragma unroll
  for (int i = 0; i < 4; ++i)
#pragma unroll
    for (int r = 0; r < 4; ++r) {
      float m = fmaxf(fmaxf(acc[i][0][r], acc[i][1][r]),
                      fmaxf(acc[i][2][r], acc[i][3][r]));
      m = fmaxf(m, __shfl_xor(m, 1));
      m = fmaxf(m, __shfl_xor(m, 2));
      m = fmaxf(m, __shfl_xor(m, 4));
      m = fmaxf(m, __shfl_xor(m, 8));
      if (fr == 0) redm[wave][i * 16 + g4 + r] = m;
    }
  __syncthreads();
  float M[4][4];
#pragma unroll
  for (int i = 0; i < 4; ++i)
#pragma unroll
    for (int r = 0; r < 4; ++r) {
      int row = i * 16 + g4 + r;
      float m = redm[0][row];
#pragma unroll
      for (int w = 1; w < 8; ++w) m = fmaxf(m, redm[w][row]);
      M[i][r] = m;
    }
  // exp + per-row sum
#pragma unroll
  for (int i = 0; i < 4; ++i)
#pragma unroll
    for (int r = 0; r < 4; ++r) {
      float s = 0.f;
#pragma unroll
      for (int j = 0; j < 4; ++j) {
        float e = __expf(acc[i][j][r] - M[i][r]);
        acc[i][j][r] = e;
        s += e;
      }
      s += __shfl_xor(s, 1);
      s += __shfl_xor(s, 2);
      s += __shfl_xor(s, 4);
      s += __shfl_xor(s, 8);
      if (fr == 0) reds[wave][i * 16 + g4 + r] = s;
    }
  __syncthreads();
#pragma unroll
  for (int i = 0; i < 4; ++i)
#pragma unroll
    for (int r = 0; r < 4; ++r) {
      int row = i * 16 + g4 + r;
      float s = reds[0][row];
#pragma unroll
      for (int w = 1; w < 8; ++w) s += reds[w][row];
      float inv = 1.0f / s;
#pragma unroll
      for (int j = 0; j < 4; ++j)
        Ab[(size_t)(bm + row) * L + wn + j * 16 + fr] =
            (_Float16)(acc[i][j][r] * inv);
    }
}

// -------- yT: yh [b,512,768] fp16 -> yT [b,768,512] fp16 (bit moves) ------
__global__ __launch_bounds__(256) void yT_kernel(
    const _Float16* __restrict__ Yh, _Float16* __restrict__ YT) {
  __shared__ unsigned short T[64][65];
  int b = blockIdx.z;
  int n0 = blockIdx.x * 64, h0 = blockIdx.y * 64;
  const unsigned short* Yb = (const unsigned short*)Yh + (size_t)b * 512 * 768;
  unsigned short* Tb = (unsigned short*)YT + (size_t)b * 768 * 512;
  int tid = threadIdx.x;
  int r = tid >> 4, c = (tid & 15) << 2;
#pragma unroll
  for (int i = 0; i < 4; ++i) {
    int rr = r + i * 16;
    ushort4 v = *(const ushort4*)&Yb[(size_t)(n0 + rr) * 768 + h0 + c];
    T[c + 0][rr] = v.x;
    T[c + 1][rr] = v.y;
    T[c + 2][rr] = v.z;
    T[c + 3][rr] = v.w;
  }
  __syncthreads();
  int hr = tid >> 2, nc = (tid & 3) << 4;
  unsigned short tmp[16];
#pragma unroll
  for (int j = 0; j < 16; ++j) tmp[j] = T[hr][nc + j];
  unsigned short* dst = &Tb[(size_t)(h0 + hr) * 512 + n0 + nc];
  *(uint4*)&dst[0] = *(uint4*)&tmp[0];
  *(uint4*)&dst[8] = *(uint4*)&tmp[8];
}

// ---- attn: O[b,512,768] = alpha @ y, K=512, fp16 MFMA --------------------
__global__ __launch_bounds__(256) void attn_mfma_kernel(
    const _Float16* __restrict__ Alpha, const _Float16* __restrict__ YT,
    float* __restrict__ O) {
  const int L = 512, H = 768;
  __shared__ _Float16 As[128 * 32], Bs[128 * 32];
  int b = blockIdx.z;
  const _Float16* Ab = Alpha + (size_t)b * L * L;
  const _Float16* Yb = YT + (size_t)b * H * L;
  float* Ob = O + (size_t)b * L * H;
  int bm = blockIdx.x * 128, bn = blockIdx.y * 128;
  int tid = threadIdx.x, lane = tid & 63, wave = tid >> 6;
  int wm = (wave & 1) * 64, wn = (wave >> 1) * 64;
  int fr = lane & 15, fk = (lane >> 4) * 8;
  int lrow = lane >> 2, lcol = (lane & 3) << 3;

  f32x4 acc[4][4];
#pragma unroll
  for (int i = 0; i < 4; ++i)
#pragma unroll
    for (int j = 0; j < 4; ++j)
#pragma unroll
      for (int e = 0; e < 4; ++e) acc[i][j][e] = 0.f;

  for (int k0 = 0; k0 < L; k0 += 32) {
    __syncthreads();
#pragma unroll
    for (int t = 0; t < 2; ++t) {
      int row = wave * 32 + t * 16;
      gld_lds16(&Ab[(size_t)(bm + row + lrow) * L + k0 + lcol], &As[row * 32]);
      gld_lds16(&Yb[(size_t)(bn + row + lrow) * L + k0 + lcol], &Bs[row * 32]);
    }
    __syncthreads();
    f16x8 a[4], bb[4];
#pragma unroll
    for (int i = 0; i < 4; ++i) {
      a[i] = *(const f16x8*)&As[(wm + i * 16 + fr) * 32 + fk];
      bb[i] = *(const f16x8*)&Bs[(wn + i * 16 + fr) * 32 + fk];
    }
#pragma unroll
    for (int i = 0; i < 4; ++i)
#pragma unroll
      for (int j = 0; j < 4; ++j)
        acc[i][j] = __builtin_amdgcn_mfma_f32_16x16x32_f16(a[i], bb[j], acc[i][j], 0, 0, 0);
  }
#pragma unroll
  for (int i = 0; i < 4; ++i)
#pragma unroll
    for (int r = 0; r < 4; ++r) {
      int m = bm + wm + i * 16 + (lane >> 4) * 4 + r;
#pragma unroll
      for (int j = 0; j < 4; ++j) {
        int h = bn + wn + j * 16 + fr;
        Ob[(size_t)m * H + h] = acc[i][j][r];
      }
    }
}

extern "C" void kernel_launch(void* const* d_in, const int* in_sizes, int n_in,
                              void* d_out, int out_size, void* d_ws, size_t ws_size,
                              hipStream_t stream) {
  const float* x = (const float*)d_in[0];   // [32,512,768]
  const float* y = (const float*)d_in[1];   // [32,512,768]
  const int* y_mask = (const int*)d_in[2];  // [32,512]
  const float* W = (const float*)d_in[3];   // [768,768]
  const float* b = (const float*)d_in[4];   // [768]
  float* out = (float*)d_out;               // [32,512,768]

  const size_t E = (size_t)16384 * 768;     // 12,582,912 elems / fp16 plane
  _Float16* xh = (_Float16*)d_ws;           // 25.2 MB
  _Float16* yh = xh + E;                    // 25.2 MB
  _Float16* Px = yh + E;                    // 25.2 MB
  _Float16* Py = Px + E;                    // 25.2 MB
  _Float16* Wh = Py + E;                    // 1.2 MB
  _Float16* alpha = xh;                     // overlays xh (dead after proj)
  _Float16* yT = Px;                        // overlays Px (dead after scores)

  dim3 blk(256);
  cvt_xy_kernel<<<dim3(6144, 2), blk, 0, stream>>>(x, y, xh, yh);
  cvt_f16_kernel<<<dim3(288), blk, 0, stream>>>(W, Wh);
  proj_mfma_kernel<<<dim3(128, 6, 2), blk, 0, stream>>>(xh, yh, Wh, b, Px, Py);
  scores_softmax_kernel<<<dim3(8, 32), dim3(512), 0, stream>>>(Px, Py, y_mask, alpha);
  yT_kernel<<<dim3(8, 12, 32), blk, 0, stream>>>(yh, yT);
  attn_mfma_kernel<<<dim3(4, 6, 32), blk, 0, stream>>>(alpha, yT, out);
}